// Round 9
// baseline (288.324 us; speedup 1.0000x reference)
//
#include <hip/hip_runtime.h>

#define N_NODES 100000
#define N_CLASS 64          // NUM_CLASS + 1
#define N_EDGES 1600000
#define HALF_E  800000      // N_EDGES / 2
#define CAP_C   36          // per-chunk padded-CSR slots (Poisson(8): P(deg>=36) ~ 1e-13)
#define CAP     64          // fallback path CAP
#define OVF_MAX 1024

typedef float f4 __attribute__((ext_vector_type(4)));

// ================= Path A': LLC-chunked pipeline =================
// ws: cnt0[N] | cnt1[N] | ovf_cnt[1] | ovf[OVF_MAX] | slots0[N*CAP_C] | slots1[N*CAP_C]

// Streams poss_edge[e_beg,e_end) -> pe_out (coalesced 1KB blocks) while building
// the per-chunk padded CSR. Loads are REGULAR (want LLC residency for the
// following gather); stores are nontemporal (minimize cache pollution).
__global__ __launch_bounds__(256) void fillcopy_chunk_kernel(
        const int* __restrict__ edges,
        const float* __restrict__ poss_edge,
        float* __restrict__ pe_out,
        int* __restrict__ cnt,
        int* __restrict__ slots,
        int* __restrict__ ovf_cnt,
        int* __restrict__ ovf,
        int e_beg, int e_end) {
    const int wave   = (blockIdx.x * blockDim.x + threadIdx.x) >> 6;
    const int lane   = threadIdx.x & 63;
    const int grp    = lane >> 4;        // edge 0..3 within the 4-edge step
    const int q      = lane & 15;        // class quad
    const int nwaves = (gridDim.x * blockDim.x) >> 6;
    const int2* e2   = (const int2*)edges;

    for (int base = e_beg + wave * 4; base < e_end; base += nwaves * 4) {
        const int e = base + grp;        // chunk sizes % 4 == 0
        const f4 a = *((const f4*)(poss_edge + (size_t)e * N_CLASS) + q);  // cacheable
        __builtin_nontemporal_store(a, (f4*)(pe_out + (size_t)e * N_CLASS) + q);
        if (q == 0) {
            const int src = e2[e].x;
            const int pos = atomicAdd(&cnt[src], 1);
            if (pos < CAP_C) {
                slots[src * CAP_C + pos] = e;
            } else {
                const int k = atomicAdd(ovf_cnt, 1);
                if (k < OVF_MAX) ovf[k] = e;
            }
        }
    }
}

// Per-chunk gather: one wave per node, random row reads (hopefully LLC-hot).
// FINAL=0: write raw partial sum. FINAL=1: add previous partial, divide, write.
template <int FINAL>
__global__ __launch_bounds__(256) void gather_chunk_kernel(
        const int* __restrict__ cnt,
        const int* __restrict__ slots,
        const float* __restrict__ weights,
        const float* __restrict__ poss_edge,
        const float* __restrict__ nsum,
        float* __restrict__ acc) {
    const int node = blockIdx.x * 4 + (threadIdx.x >> 6);
    const int lane = threadIdx.x & 63;
    const int grp  = lane >> 4;
    const int q    = lane & 15;
    if (node >= N_NODES) return;

    const int n = min(cnt[node], CAP_C);
    const int* ids = slots + node * CAP_C;

    f4 val = (f4)(0.0f);
    int j = 0;
    for (; j + 8 <= n; j += 8) {
        const int e0 = ids[j + grp];
        const int e1 = ids[j + 4 + grp];
        const float w0 = weights[e0], w1 = weights[e1];
        const f4 a0 = *((const f4*)(poss_edge + (size_t)e0 * N_CLASS) + q);
        const f4 a1 = *((const f4*)(poss_edge + (size_t)e1 * N_CLASS) + q);
        val += a0 * w0;
        val += a1 * w1;
    }
    for (; j + 4 <= n; j += 4) {
        const int e = ids[j + grp];
        const f4 a = *((const f4*)(poss_edge + (size_t)e * N_CLASS) + q);
        val += a * weights[e];
    }
    if (j < n && grp < n - j) {
        const int e = ids[j + grp];
        const f4 a = *((const f4*)(poss_edge + (size_t)e * N_CLASS) + q);
        val += a * weights[e];
    }

    val.x += __shfl_xor(val.x, 16); val.y += __shfl_xor(val.y, 16);
    val.z += __shfl_xor(val.z, 16); val.w += __shfl_xor(val.w, 16);
    val.x += __shfl_xor(val.x, 32); val.y += __shfl_xor(val.y, 32);
    val.z += __shfl_xor(val.z, 32); val.w += __shfl_xor(val.w, 32);

    if (grp == 0) {
        f4* dst = (f4*)(acc + (size_t)node * N_CLASS) + q;
        if (FINAL) {
            const f4 prev = *dst;
            const float inv = 1.0f / nsum[node];
            *dst = (val + prev) * inv;
        } else {
            *dst = val;
        }
    }
}

// Overflow edges (none in practice): exact atomic adds after the final gather.
__global__ void cleanup_kernel(const int* __restrict__ ovf_cnt, const int* __restrict__ ovf,
                               const int* __restrict__ edges,
                               const float* __restrict__ weights,
                               const float* __restrict__ poss_edge,
                               const float* __restrict__ nsum,
                               float* __restrict__ acc) {
    const int m = min(*ovf_cnt, OVF_MAX);
    for (int t = threadIdx.x; t < m * 16; t += blockDim.x) {
        const int k = t >> 4, q = t & 15;
        const int e = ovf[k];
        const int src = edges[2 * e];
        const float w = weights[e];
        const f4 a = *((const f4*)(poss_edge + (size_t)e * N_CLASS) + q);
        const float inv = 1.0f / nsum[src];
        float* base = acc + (size_t)src * N_CLASS + q * 4;
        atomicAdd(base + 0, a.x * w * inv);
        atomicAdd(base + 1, a.y * w * inv);
        atomicAdd(base + 2, a.z * w * inv);
        atomicAdd(base + 3, a.w * w * inv);
    }
}

// ================= Path A: R8 padded-CSR (fallback, 26 MB ws) =================
__global__ __launch_bounds__(256) void fillcopy_kernel(
        const int* __restrict__ edges,
        const float* __restrict__ poss_edge,
        float* __restrict__ pe_out,
        int* __restrict__ cnt,
        int* __restrict__ slots,
        int* __restrict__ ovf_cnt,
        int* __restrict__ ovf) {
    const int wave   = (blockIdx.x * blockDim.x + threadIdx.x) >> 6;
    const int lane   = threadIdx.x & 63;
    const int grp    = lane >> 4;
    const int q      = lane & 15;
    const int nwaves = (gridDim.x * blockDim.x) >> 6;
    const int2* e2   = (const int2*)edges;

    for (int base = wave * 4; base < N_EDGES; base += nwaves * 4) {
        const int e = base + grp;
        const f4 a = __builtin_nontemporal_load((const f4*)(poss_edge + (size_t)e * N_CLASS) + q);
        __builtin_nontemporal_store(a, (f4*)(pe_out + (size_t)e * N_CLASS) + q);
        if (q == 0) {
            const int src = e2[e].x;
            const int pos = atomicAdd(&cnt[src], 1);
            if (pos < CAP) {
                slots[src * CAP + pos] = e;
            } else {
                const int k = atomicAdd(ovf_cnt, 1);
                if (k < OVF_MAX) ovf[k] = e;
            }
        }
    }
}

__global__ __launch_bounds__(256) void gather_padded_kernel(
        const int* __restrict__ cnt,
        const int* __restrict__ slots,
        const float* __restrict__ weights,
        const float* __restrict__ poss_edge,
        const float* __restrict__ nsum,
        float* __restrict__ acc) {
    const int node = blockIdx.x * 4 + (threadIdx.x >> 6);
    const int lane = threadIdx.x & 63;
    const int grp  = lane >> 4;
    const int q    = lane & 15;
    if (node >= N_NODES) return;

    const int n = min(cnt[node], CAP);
    const int* ids = slots + node * CAP;

    f4 val = (f4)(0.0f);
    int j = 0;
    for (; j + 16 <= n; j += 16) {
        const int e0 = ids[j + grp];
        const int e1 = ids[j + 4 + grp];
        const int e2 = ids[j + 8 + grp];
        const int e3 = ids[j + 12 + grp];
        const float w0 = weights[e0], w1 = weights[e1];
        const float w2 = weights[e2], w3 = weights[e3];
        const f4 a0 = __builtin_nontemporal_load((const f4*)(poss_edge + (size_t)e0 * N_CLASS) + q);
        const f4 a1 = __builtin_nontemporal_load((const f4*)(poss_edge + (size_t)e1 * N_CLASS) + q);
        const f4 a2 = __builtin_nontemporal_load((const f4*)(poss_edge + (size_t)e2 * N_CLASS) + q);
        const f4 a3 = __builtin_nontemporal_load((const f4*)(poss_edge + (size_t)e3 * N_CLASS) + q);
        val += a0 * w0;
        val += a1 * w1;
        val += a2 * w2;
        val += a3 * w3;
    }
    for (; j + 4 <= n; j += 4) {
        const int e = ids[j + grp];
        const f4 a = __builtin_nontemporal_load((const f4*)(poss_edge + (size_t)e * N_CLASS) + q);
        val += a * weights[e];
    }
    if (j < n && grp < n - j) {
        const int e = ids[j + grp];
        const f4 a = __builtin_nontemporal_load((const f4*)(poss_edge + (size_t)e * N_CLASS) + q);
        val += a * weights[e];
    }

    val.x += __shfl_xor(val.x, 16); val.y += __shfl_xor(val.y, 16);
    val.z += __shfl_xor(val.z, 16); val.w += __shfl_xor(val.w, 16);
    val.x += __shfl_xor(val.x, 32); val.y += __shfl_xor(val.y, 32);
    val.z += __shfl_xor(val.z, 32); val.w += __shfl_xor(val.w, 32);

    if (grp == 0) {
        const float inv = 1.0f / nsum[node];
        f4 o = val * inv;
        *reinterpret_cast<f4*>(acc + (size_t)node * N_CLASS + q * 4) = o;
    }
}

// ================= fallback: atomic scatter (tiny ws) =================
__global__ void scatter_copy_kernel(const int* __restrict__ edges,
                                    const float* __restrict__ weights,
                                    const float* __restrict__ poss_edge,
                                    float* __restrict__ acc,
                                    float* __restrict__ pe_out) {
    const int total = N_EDGES * 16;
    const int stride = gridDim.x * blockDim.x;
    for (int t = blockIdx.x * blockDim.x + threadIdx.x; t < total; t += stride) {
        const int e  = t >> 4;
        const int c0 = (t & 15) << 2;
        const float4 pe = *reinterpret_cast<const float4*>(poss_edge + (size_t)e * N_CLASS + c0);
        const float  w  = weights[e];
        const int    src = edges[2 * e];
        *reinterpret_cast<float4*>(pe_out + (size_t)e * N_CLASS + c0) = pe;
        float* a = acc + (size_t)src * N_CLASS + c0;
        atomicAdd(a + 0, pe.x * w);
        atomicAdd(a + 1, pe.y * w);
        atomicAdd(a + 2, pe.z * w);
        atomicAdd(a + 3, pe.w * w);
    }
}

__global__ void divide_kernel(float* __restrict__ acc,
                              const float* __restrict__ nsum) {
    const int t = blockIdx.x * blockDim.x + threadIdx.x;
    if (t >= N_NODES * 16) return;
    const int   node = t >> 4;
    const float d    = nsum[node];
    float4 v = *reinterpret_cast<float4*>(acc + (size_t)t * 4);
    v.x /= d; v.y /= d; v.z /= d; v.w /= d;
    *reinterpret_cast<float4*>(acc + (size_t)t * 4) = v;
}

extern "C" void kernel_launch(void* const* d_in, const int* in_sizes, int n_in,
                              void* d_out, int out_size, void* d_ws, size_t ws_size,
                              hipStream_t stream) {
    const int*   edges     = (const int*)d_in[0];
    const float* weights   = (const float*)d_in[1];
    const float* poss_edge = (const float*)d_in[2];
    const float* nsum      = (const float*)d_in[3];

    float* out    = (float*)d_out;
    float* acc    = out;                                   // N_NODES*64 floats
    float* pe_out = out + (size_t)N_NODES * N_CLASS;

    const size_t ws_chunk =
        (size_t)(2 * N_NODES + 1 + OVF_MAX + 2 * (size_t)N_NODES * CAP_C) * sizeof(int); // ~29.6 MB
    const size_t ws_A =
        (size_t)(N_NODES + 1 + OVF_MAX + (size_t)N_NODES * CAP) * sizeof(int);           // ~26 MB

    if (ws_size >= ws_chunk) {
        int* cnt0    = (int*)d_ws;                         // N_NODES
        int* cnt1    = cnt0 + N_NODES;                     // N_NODES
        int* ovf_cnt = cnt1 + N_NODES;                     // 1
        int* ovf     = ovf_cnt + 1;                        // OVF_MAX
        int* slots0  = ovf + OVF_MAX;                      // N_NODES*CAP_C
        int* slots1  = slots0 + (size_t)N_NODES * CAP_C;   // N_NODES*CAP_C

        (void)hipMemsetAsync(cnt0, 0, (size_t)(2 * N_NODES + 1) * sizeof(int), stream);

        // chunk 0: stream first half of poss_edge, then gather it while LLC-hot
        fillcopy_chunk_kernel<<<8192, 256, 0, stream>>>(
            edges, poss_edge, pe_out, cnt0, slots0, ovf_cnt, ovf, 0, HALF_E);
        gather_chunk_kernel<0><<<(N_NODES + 3) / 4, 256, 0, stream>>>(
            cnt0, slots0, weights, poss_edge, nsum, acc);

        // chunk 1
        fillcopy_chunk_kernel<<<8192, 256, 0, stream>>>(
            edges, poss_edge, pe_out, cnt1, slots1, ovf_cnt, ovf, HALF_E, N_EDGES);
        gather_chunk_kernel<1><<<(N_NODES + 3) / 4, 256, 0, stream>>>(
            cnt1, slots1, weights, poss_edge, nsum, acc);

        cleanup_kernel<<<1, 256, 0, stream>>>(
            ovf_cnt, ovf, edges, weights, poss_edge, nsum, acc);
    } else if (ws_size >= ws_A) {
        int* cnt     = (int*)d_ws;
        int* ovf_cnt = cnt + N_NODES;
        int* ovf     = ovf_cnt + 1;
        int* slots   = ovf + OVF_MAX;

        (void)hipMemsetAsync(cnt, 0, (size_t)(N_NODES + 1) * sizeof(int), stream);
        fillcopy_kernel<<<8192, 256, 0, stream>>>(
            edges, poss_edge, pe_out, cnt, slots, ovf_cnt, ovf);
        gather_padded_kernel<<<(N_NODES + 3) / 4, 256, 0, stream>>>(
            cnt, slots, weights, poss_edge, nsum, acc);
        cleanup_kernel<<<1, 256, 0, stream>>>(
            ovf_cnt, ovf, edges, weights, poss_edge, nsum, acc);
    } else {
        (void)hipMemsetAsync(acc, 0, (size_t)N_NODES * N_CLASS * sizeof(float), stream);
        scatter_copy_kernel<<<8192, 256, 0, stream>>>(edges, weights, poss_edge, acc, pe_out);
        const int div_threads = N_NODES * 16;
        divide_kernel<<<(div_threads + 255) / 256, 256, 0, stream>>>(acc, nsum);
    }
}

// Round 10
// 276.177 us; speedup vs baseline: 1.0440x; 1.0440x over previous
//
#include <hip/hip_runtime.h>

#define N_NODES 100000
#define N_CLASS 64          // NUM_CLASS + 1
#define N_EDGES 1600000
#define CAP     64          // padded-CSR slots per node (Poisson-16 max degree ~45)
#define OVF_MAX 1024
#define SCAN_NB 200
#define SCAN_T  256

typedef float f4 __attribute__((ext_vector_type(4)));

// ================= Path A: padded CSR, copy fused into fill =================
// ws layout A: cnt[N_NODES] | ovf_cnt[1] | ovf[OVF_MAX] | slots[N_NODES*CAP]

// Streams poss_edge -> pe_out sequentially (full-BW copy) while building the
// padded CSR. Wave layout: grp = lane>>4 picks one of 4 CONSECUTIVE edges,
// q = lane&15 picks the float4 class-quad -> each load/store inst moves a
// fully-coalesced 1KB block. Lanes with q==0 do the slot placement.
__global__ __launch_bounds__(256) void fillcopy_kernel(
        const int* __restrict__ edges,
        const float* __restrict__ poss_edge,
        float* __restrict__ pe_out,
        int* __restrict__ cnt,
        int* __restrict__ slots,
        int* __restrict__ ovf_cnt,
        int* __restrict__ ovf) {
    const int wave   = (blockIdx.x * blockDim.x + threadIdx.x) >> 6;
    const int lane   = threadIdx.x & 63;
    const int grp    = lane >> 4;        // edge 0..3 within the 4-edge step
    const int q      = lane & 15;        // class quad
    const int nwaves = (gridDim.x * blockDim.x) >> 6;
    const int2* e2   = (const int2*)edges;

    for (int base = wave * 4; base < N_EDGES; base += nwaves * 4) {
        const int e = base + grp;        // N_EDGES % 4 == 0, always in range
        const f4 a = __builtin_nontemporal_load((const f4*)(poss_edge + (size_t)e * N_CLASS) + q);
        __builtin_nontemporal_store(a, (f4*)(pe_out + (size_t)e * N_CLASS) + q);
        if (q == 0) {
            const int src = e2[e].x;
            const int pos = atomicAdd(&cnt[src], 1);
            if (pos < CAP) {
                slots[src * CAP + pos] = e;
            } else {
                const int k = atomicAdd(ovf_cnt, 1);
                if (k < OVF_MAX) ovf[k] = e;
            }
        }
    }
}

// Read-only random gather: one wave per node; grp picks one of 4 edges,
// q picks the class quad. 16-edge superstep = 4 x 1KB row loads in flight.
// No pe_out stores (copy already done in fillcopy).
__global__ __launch_bounds__(256) void gather_padded_kernel(
        const int* __restrict__ cnt,
        const int* __restrict__ slots,
        const float* __restrict__ weights,
        const float* __restrict__ poss_edge,
        const float* __restrict__ nsum,
        float* __restrict__ acc) {
    const int node = blockIdx.x * 4 + (threadIdx.x >> 6);
    const int lane = threadIdx.x & 63;
    const int grp  = lane >> 4;
    const int q    = lane & 15;
    if (node >= N_NODES) return;

    const int n = min(cnt[node], CAP);
    const int* ids = slots + node * CAP;

    f4 val = (f4)(0.0f);
    int j = 0;
    for (; j + 16 <= n; j += 16) {
        const int e0 = ids[j + grp];
        const int e1 = ids[j + 4 + grp];
        const int e2 = ids[j + 8 + grp];
        const int e3 = ids[j + 12 + grp];
        const float w0 = weights[e0], w1 = weights[e1];
        const float w2 = weights[e2], w3 = weights[e3];
        const f4 a0 = __builtin_nontemporal_load((const f4*)(poss_edge + (size_t)e0 * N_CLASS) + q);
        const f4 a1 = __builtin_nontemporal_load((const f4*)(poss_edge + (size_t)e1 * N_CLASS) + q);
        const f4 a2 = __builtin_nontemporal_load((const f4*)(poss_edge + (size_t)e2 * N_CLASS) + q);
        const f4 a3 = __builtin_nontemporal_load((const f4*)(poss_edge + (size_t)e3 * N_CLASS) + q);
        val += a0 * w0;
        val += a1 * w1;
        val += a2 * w2;
        val += a3 * w3;
    }
    for (; j + 4 <= n; j += 4) {
        const int e = ids[j + grp];
        const f4 a = __builtin_nontemporal_load((const f4*)(poss_edge + (size_t)e * N_CLASS) + q);
        val += a * weights[e];
    }
    if (j < n && grp < n - j) {
        const int e = ids[j + grp];
        const f4 a = __builtin_nontemporal_load((const f4*)(poss_edge + (size_t)e * N_CLASS) + q);
        val += a * weights[e];
    }

    val.x += __shfl_xor(val.x, 16); val.y += __shfl_xor(val.y, 16);
    val.z += __shfl_xor(val.z, 16); val.w += __shfl_xor(val.w, 16);
    val.x += __shfl_xor(val.x, 32); val.y += __shfl_xor(val.y, 32);
    val.z += __shfl_xor(val.z, 32); val.w += __shfl_xor(val.w, 32);

    if (grp == 0) {
        const float inv = 1.0f / nsum[node];
        f4 o = val * inv;
        *reinterpret_cast<f4*>(acc + (size_t)node * N_CLASS + q * 4) = o;
    }
}

// Handles any overflow edges (none for this graph): atomic adds into acc.
// Runs after gather (gather's plain acc store must land first).
__global__ void cleanup_kernel(const int* __restrict__ ovf_cnt, const int* __restrict__ ovf,
                               const int* __restrict__ edges,
                               const float* __restrict__ weights,
                               const float* __restrict__ poss_edge,
                               const float* __restrict__ nsum,
                               float* __restrict__ acc) {
    const int m = min(*ovf_cnt, OVF_MAX);
    for (int t = threadIdx.x; t < m * 16; t += blockDim.x) {
        const int k = t >> 4, q = t & 15;
        const int e = ovf[k];
        const int src = edges[2 * e];
        const float w = weights[e];
        const f4 a = *((const f4*)(poss_edge + (size_t)e * N_CLASS) + q);
        const float inv = 1.0f / nsum[src];
        float* base = acc + (size_t)src * N_CLASS + q * 4;
        atomicAdd(base + 0, a.x * w * inv);
        atomicAdd(base + 1, a.y * w * inv);
        atomicAdd(base + 2, a.z * w * inv);
        atomicAdd(base + 3, a.w * w * inv);
    }
}

// ================= Path B: compact CSR (R5 structure, smaller ws) =================
// ws layout B: offsets [N_NODES+1] | cursor [N_NODES] | bsum [256] | edge_ids [N_EDGES]

__global__ void hist_kernel(const int* __restrict__ edges, int* __restrict__ counts) {
    const int stride = gridDim.x * blockDim.x;
    const int2* e2 = (const int2*)edges;
    for (int e = blockIdx.x * blockDim.x + threadIdx.x; e < N_EDGES; e += stride)
        atomicAdd(&counts[e2[e].x], 1);
}

__global__ void scanA_kernel(const int* __restrict__ counts, int* __restrict__ bsum) {
    __shared__ int s[SCAN_T];
    const int b = blockIdx.x, t = threadIdx.x;
    const int i0 = b * 512 + 2 * t;
    int c0 = (i0     < N_NODES) ? counts[i0]     : 0;
    int c1 = (i0 + 1 < N_NODES) ? counts[i0 + 1] : 0;
    s[t] = c0 + c1;
    __syncthreads();
    for (int d = SCAN_T / 2; d > 0; d >>= 1) {
        if (t < d) s[t] += s[t + d];
        __syncthreads();
    }
    if (t == 0) bsum[b] = s[0];
}

__global__ void scanB_kernel(int* __restrict__ bsum, int* __restrict__ offsets) {
    __shared__ int s[SCAN_T];
    const int t = threadIdx.x;
    const int v = (t < SCAN_NB) ? bsum[t] : 0;
    s[t] = v;
    __syncthreads();
    for (int d = 1; d < SCAN_T; d <<= 1) {
        int x = (t >= d) ? s[t - d] : 0;
        __syncthreads();
        s[t] += x;
        __syncthreads();
    }
    if (t < SCAN_NB) bsum[t] = s[t] - v;
    if (t == SCAN_T - 1) offsets[N_NODES] = s[t];
}

__global__ void scanC_kernel(int* __restrict__ offsets, const int* __restrict__ bsum,
                             int* __restrict__ cursor) {
    __shared__ int s[SCAN_T];
    const int b = blockIdx.x, t = threadIdx.x;
    const int i0 = b * 512 + 2 * t;
    int c0 = (i0     < N_NODES) ? offsets[i0]     : 0;
    int c1 = (i0 + 1 < N_NODES) ? offsets[i0 + 1] : 0;
    const int pair = c0 + c1;
    s[t] = pair;
    __syncthreads();
    for (int d = 1; d < SCAN_T; d <<= 1) {
        int x = (t >= d) ? s[t - d] : 0;
        __syncthreads();
        s[t] += x;
        __syncthreads();
    }
    const int excl = s[t] - pair + bsum[b];
    if (i0 < N_NODES)     { offsets[i0]     = excl;      cursor[i0]     = excl; }
    if (i0 + 1 < N_NODES) { offsets[i0 + 1] = excl + c0; cursor[i0 + 1] = excl + c0; }
}

__global__ void place_kernel(const int* __restrict__ edges,
                             int* __restrict__ cursor,
                             int* __restrict__ edge_ids) {
    const int stride = gridDim.x * blockDim.x;
    const int2* e2 = (const int2*)edges;
    for (int e = blockIdx.x * blockDim.x + threadIdx.x; e < N_EDGES; e += stride) {
        const int src = e2[e].x;
        const int pos = atomicAdd(&cursor[src], 1);
        edge_ids[pos] = e;
    }
}

__global__ __launch_bounds__(256) void gather_csr_kernel(
        const int* __restrict__ offsets,
        const int* __restrict__ edge_ids,
        const float* __restrict__ weights,
        const float* __restrict__ poss_edge,
        const float* __restrict__ nsum,
        float* __restrict__ acc,
        float* __restrict__ pe_out) {
    const int node = blockIdx.x * 4 + (threadIdx.x >> 6);
    const int lane = threadIdx.x & 63;
    const int grp  = lane >> 4;
    const int q    = lane & 15;
    if (node >= N_NODES) return;
    const int beg = offsets[node];
    const int n   = offsets[node + 1] - beg;
    const int* ids = edge_ids + beg;

    f4 val = (f4)(0.0f);
    int j = 0;
    for (; j + 4 <= n; j += 4) {
        const int e = ids[j + grp];
        const float w = weights[e];
        const f4 a = __builtin_nontemporal_load((const f4*)(poss_edge + (size_t)e * N_CLASS) + q);
        __builtin_nontemporal_store(a, (f4*)(pe_out + (size_t)e * N_CLASS) + q);
        val += a * w;
    }
    if (j < n && grp < n - j) {
        const int e = ids[j + grp];
        const float w = weights[e];
        const f4 a = __builtin_nontemporal_load((const f4*)(poss_edge + (size_t)e * N_CLASS) + q);
        __builtin_nontemporal_store(a, (f4*)(pe_out + (size_t)e * N_CLASS) + q);
        val += a * w;
    }

    val.x += __shfl_xor(val.x, 16); val.y += __shfl_xor(val.y, 16);
    val.z += __shfl_xor(val.z, 16); val.w += __shfl_xor(val.w, 16);
    val.x += __shfl_xor(val.x, 32); val.y += __shfl_xor(val.y, 32);
    val.z += __shfl_xor(val.z, 32); val.w += __shfl_xor(val.w, 32);

    if (grp == 0) {
        const float inv = 1.0f / nsum[node];
        f4 o = val * inv;
        *reinterpret_cast<f4*>(acc + (size_t)node * N_CLASS + q * 4) = o;
    }
}

// ================= fallback: atomic scatter (tiny ws) =================
__global__ void scatter_copy_kernel(const int* __restrict__ edges,
                                    const float* __restrict__ weights,
                                    const float* __restrict__ poss_edge,
                                    float* __restrict__ acc,
                                    float* __restrict__ pe_out) {
    const int total = N_EDGES * 16;
    const int stride = gridDim.x * blockDim.x;
    for (int t = blockIdx.x * blockDim.x + threadIdx.x; t < total; t += stride) {
        const int e  = t >> 4;
        const int c0 = (t & 15) << 2;
        const float4 pe = *reinterpret_cast<const float4*>(poss_edge + (size_t)e * N_CLASS + c0);
        const float  w  = weights[e];
        const int    src = edges[2 * e];
        *reinterpret_cast<float4*>(pe_out + (size_t)e * N_CLASS + c0) = pe;
        float* a = acc + (size_t)src * N_CLASS + c0;
        atomicAdd(a + 0, pe.x * w);
        atomicAdd(a + 1, pe.y * w);
        atomicAdd(a + 2, pe.z * w);
        atomicAdd(a + 3, pe.w * w);
    }
}

__global__ void divide_kernel(float* __restrict__ acc,
                              const float* __restrict__ nsum) {
    const int t = blockIdx.x * blockDim.x + threadIdx.x;
    if (t >= N_NODES * 16) return;
    const int   node = t >> 4;
    const float d    = nsum[node];
    float4 v = *reinterpret_cast<float4*>(acc + (size_t)t * 4);
    v.x /= d; v.y /= d; v.z /= d; v.w /= d;
    *reinterpret_cast<float4*>(acc + (size_t)t * 4) = v;
}

extern "C" void kernel_launch(void* const* d_in, const int* in_sizes, int n_in,
                              void* d_out, int out_size, void* d_ws, size_t ws_size,
                              hipStream_t stream) {
    const int*   edges     = (const int*)d_in[0];
    const float* weights   = (const float*)d_in[1];
    const float* poss_edge = (const float*)d_in[2];
    const float* nsum      = (const float*)d_in[3];

    float* out    = (float*)d_out;
    float* acc    = out;                                   // N_NODES*64 floats
    float* pe_out = out + (size_t)N_NODES * N_CLASS;

    const size_t ws_A =
        (size_t)(N_NODES + 1 + OVF_MAX + (size_t)N_NODES * CAP) * sizeof(int); // ~26 MB
    const size_t ws_B =
        (size_t)(N_NODES + 1 + N_NODES + 256 + N_EDGES) * sizeof(int);         // ~7.2 MB

    if (ws_size >= ws_A) {
        int* cnt     = (int*)d_ws;                         // N_NODES
        int* ovf_cnt = cnt + N_NODES;                      // 1
        int* ovf     = ovf_cnt + 1;                        // OVF_MAX
        int* slots   = ovf + OVF_MAX;                      // N_NODES*CAP

        (void)hipMemsetAsync(cnt, 0, (size_t)(N_NODES + 1) * sizeof(int), stream);
        fillcopy_kernel<<<8192, 256, 0, stream>>>(
            edges, poss_edge, pe_out, cnt, slots, ovf_cnt, ovf);
        gather_padded_kernel<<<(N_NODES + 3) / 4, 256, 0, stream>>>(
            cnt, slots, weights, poss_edge, nsum, acc);
        cleanup_kernel<<<1, 256, 0, stream>>>(
            ovf_cnt, ovf, edges, weights, poss_edge, nsum, acc);
    } else if (ws_size >= ws_B) {
        int* offsets  = (int*)d_ws;
        int* cursor   = offsets + (N_NODES + 1);
        int* bsum     = cursor + N_NODES;
        int* edge_ids = bsum + 256;

        (void)hipMemsetAsync(offsets, 0, (size_t)N_NODES * sizeof(int), stream);
        hist_kernel <<<2048, 256, 0, stream>>>(edges, offsets);
        scanA_kernel<<<SCAN_NB, SCAN_T, 0, stream>>>(offsets, bsum);
        scanB_kernel<<<1, SCAN_T, 0, stream>>>(bsum, offsets);
        scanC_kernel<<<SCAN_NB, SCAN_T, 0, stream>>>(offsets, bsum, cursor);
        place_kernel<<<2048, 256, 0, stream>>>(edges, cursor, edge_ids);
        gather_csr_kernel<<<(N_NODES + 3) / 4, 256, 0, stream>>>(
            offsets, edge_ids, weights, poss_edge, nsum, acc, pe_out);
    } else {
        (void)hipMemsetAsync(acc, 0, (size_t)N_NODES * N_CLASS * sizeof(float), stream);
        scatter_copy_kernel<<<8192, 256, 0, stream>>>(edges, weights, poss_edge, acc, pe_out);
        const int div_threads = N_NODES * 16;
        divide_kernel<<<(div_threads + 255) / 256, 256, 0, stream>>>(acc, nsum);
    }
}